// Round 1
// baseline (365.699 us; speedup 1.0000x reference)
//
#include <hip/hip_runtime.h>
#include <math.h>

#define B_ 8
#define N_ 32
#define M_ 32
#define HW 192

// ---------------- pool: pooled[b*N+n] = mean over HxW ----------------
__global__ __launch_bounds__(256) void pool_kernel(const float* __restrict__ x,
                                                   float* __restrict__ pooled) {
    int bn = blockIdx.x;  // 0..255 = b*32+n
    const float* p = x + (size_t)bn * (HW * HW);
    float s = 0.f;
    for (int i = threadIdx.x; i < HW * HW; i += 256) s += p[i];
#pragma unroll
    for (int off = 32; off > 0; off >>= 1) s += __shfl_down(s, off, 64);
    __shared__ float red[4];
    if ((threadIdx.x & 63) == 0) red[threadIdx.x >> 6] = s;
    __syncthreads();
    if (threadIdx.x == 0)
        pooled[bn] = (red[0] + red[1] + red[2] + red[3]) * (1.f / (HW * HW));
}

// ---------- prep: transpose weight (M,N,3,3)->wq[p][n][m]; bias MLP ----------
__global__ __launch_bounds__(256) void prep_kernel(
    const float* __restrict__ pooled, const float* __restrict__ b1w,
    const float* __restrict__ b1b, const float* __restrict__ b2w,
    const float* __restrict__ b2b, const float* __restrict__ weight,
    float* __restrict__ bias, float* __restrict__ wq) {
    int tid = threadIdx.x;
    for (int idx = tid; idx < M_ * N_ * 9; idx += 256) {
        int m = idx / (N_ * 9);
        int rem = idx % (N_ * 9);
        int n = rem / 9;
        int p = rem % 9;
        wq[(p * N_ + n) * M_ + m] = weight[idx];
    }
    int b = tid >> 5, j = tid & 31;  // 8 x 32 = 256 threads exactly
    __shared__ float hsh[B_][N_];
    float s = b1b[j];
#pragma unroll
    for (int n = 0; n < N_; n++) s += pooled[b * N_ + n] * b1w[j * N_ + n];
    hsh[b][j] = fmaxf(s, 0.f);
    __syncthreads();
    float s2 = b2b[j];
#pragma unroll
    for (int q = 0; q < M_; q++) s2 += hsh[b][q] * b2w[j * M_ + q];
    bias[b * M_ + j] = s2;
}

// ---------- fused: attention1 (in-register) + attended conv + bias ----------
__global__ __launch_bounds__(256) void laconv_kernel(
    const float* __restrict__ x, const float* __restrict__ a1w,
    const float* __restrict__ a1b, const float* __restrict__ a2w,
    const float* __restrict__ a2b, const float* __restrict__ a3w,
    const float* __restrict__ a3b, const float* __restrict__ wq,
    const float* __restrict__ bias, float* __restrict__ out) {
    __shared__ float xs[N_][18 * 18];  // 41.5 KB: 16x16 tile + halo, 32 ch
    const int b = blockIdx.z;
    const int th0 = blockIdx.y * 16, tw0 = blockIdx.x * 16;
    const int tid = threadIdx.x;
    const float* xb = x + (size_t)b * N_ * HW * HW;

    for (int n = 0; n < N_; n++) {
        for (int idx = tid; idx < 324; idx += 256) {
            int r = idx / 18, c = idx - r * 18;
            int h = th0 + r - 1, w = tw0 + c - 1;
            float v = 0.f;
            if ((unsigned)h < HW && (unsigned)w < HW)
                v = xb[n * HW * HW + h * HW + w];
            xs[n][idx] = v;
        }
    }
    __syncthreads();

    const int ty = tid >> 4, tx = tid & 15;

    // ---- attention1: conv3x3 (32->9) ----
    float aacc[9];
#pragma unroll
    for (int o = 0; o < 9; o++) aacc[o] = a1b[o];
    for (int n = 0; n < N_; n++) {
#pragma unroll
        for (int kp = 0; kp < 9; kp++) {
            const int di = kp / 3, dj = kp % 3;
            float xv = xs[n][(ty + di) * 18 + tx + dj];
#pragma unroll
            for (int o = 0; o < 9; o++)
                aacc[o] += xv * a1w[(o * N_ + n) * 9 + kp];
        }
    }
    float t1[9], t2[9], attv[9];
#pragma unroll
    for (int o = 0; o < 9; o++) t1[o] = fmaxf(aacc[o], 0.f);
#pragma unroll
    for (int o2 = 0; o2 < 9; o2++) {
        float s = a2b[o2];
#pragma unroll
        for (int o = 0; o < 9; o++) s += a2w[o2 * 9 + o] * t1[o];
        t2[o2] = fmaxf(s, 0.f);
    }
#pragma unroll
    for (int o3 = 0; o3 < 9; o3++) {
        float s = a3b[o3];
#pragma unroll
        for (int o2 = 0; o2 < 9; o2++) s += a3w[o3 * 9 + o2] * t2[o2];
        attv[o3] = 1.f / (1.f + __expf(-s));
    }

    // ---- main: y[m] = sum_{n,p} x[n, h+di-1, w+dj-1] * attv[p] * wq[p][n][m]
    float acc[M_];
#pragma unroll
    for (int m = 0; m < M_; m++) acc[m] = 0.f;
    for (int n = 0; n < N_; n++) {
        float xv[9];
#pragma unroll
        for (int kp = 0; kp < 9; kp++)
            xv[kp] = xs[n][(ty + kp / 3) * 18 + tx + kp % 3];
#pragma unroll
        for (int p = 0; p < 9; p++) {
            float t = xv[p] * attv[p];
            const float* wpn = wq + (p * N_ + n) * M_;  // uniform -> s_load
#pragma unroll
            for (int m = 0; m < M_; m++) acc[m] += t * wpn[m];
        }
    }

    const int h = th0 + ty, w = tw0 + tx;
#pragma unroll
    for (int m = 0; m < M_; m++)
        out[(((size_t)b * M_ + m) * HW + h) * HW + w] = acc[m] + bias[b * M_ + m];
}

extern "C" void kernel_launch(void* const* d_in, const int* in_sizes, int n_in,
                              void* d_out, int out_size, void* d_ws,
                              size_t ws_size, hipStream_t stream) {
    const float* x    = (const float*)d_in[0];
    const float* a1w  = (const float*)d_in[1];
    const float* a1b  = (const float*)d_in[2];
    const float* a2w  = (const float*)d_in[3];
    const float* a2b  = (const float*)d_in[4];
    const float* a3w  = (const float*)d_in[5];
    const float* a3b  = (const float*)d_in[6];
    const float* b1w  = (const float*)d_in[7];
    const float* b1b  = (const float*)d_in[8];
    const float* b2w  = (const float*)d_in[9];
    const float* b2b  = (const float*)d_in[10];
    const float* wgt  = (const float*)d_in[11];
    float* out = (float*)d_out;

    float* ws     = (float*)d_ws;
    float* pooled = ws;        // 256 floats
    float* biasv  = ws + 256;  // 256 floats
    float* wq     = ws + 512;  // 9216 floats

    pool_kernel<<<dim3(B_ * N_), dim3(256), 0, stream>>>(x, pooled);
    prep_kernel<<<dim3(1), dim3(256), 0, stream>>>(pooled, b1w, b1b, b2w, b2b,
                                                   wgt, biasv, wq);
    laconv_kernel<<<dim3(12, 12, B_), dim3(256), 0, stream>>>(
        x, a1w, a1b, a2w, a2b, a3w, a3b, wq, biasv, out);
}

// Round 3
// 165.841 us; speedup vs baseline: 2.2051x; 2.2051x over previous
//
#include <hip/hip_runtime.h>
#include <math.h>

#define B_ 8
#define N_ 32
#define M_ 32
#define HW 192

typedef __attribute__((ext_vector_type(8))) short short8;
typedef __attribute__((ext_vector_type(4))) float float4_;

__device__ inline unsigned short f2bf(float f) {
    unsigned int b = __float_as_uint(f);
    b += 0x7FFF + ((b >> 16) & 1);   // RNE
    return (unsigned short)(b >> 16);
}

union U8 { short8 s; unsigned int u[4]; };

// ---------------- pool: pooled[b*N+n] = mean over HxW ----------------
__global__ __launch_bounds__(256) void pool_kernel(const float* __restrict__ x,
                                                   float* __restrict__ pooled) {
    int bn = blockIdx.x;
    const float4_* p = (const float4_*)(x + (size_t)bn * (HW * HW));
    float s = 0.f;
    for (int i = threadIdx.x; i < (HW * HW) / 4; i += 256) {
        float4_ v = p[i];
        s += (v[0] + v[1]) + (v[2] + v[3]);
    }
#pragma unroll
    for (int off = 32; off > 0; off >>= 1) s += __shfl_down(s, off, 64);
    __shared__ float red[4];
    if ((threadIdx.x & 63) == 0) red[threadIdx.x >> 6] = s;
    __syncthreads();
    if (threadIdx.x == 0)
        pooled[bn] = (red[0] + red[1] + red[2] + red[3]) * (1.f / (HW * HW));
}

// ------- prep: MFMA A-fragments (bf16) for a1w and weight; bias MLP -------
// a1A[c][lane][j] : o=lane&15 (o<9 real, else 0), n=(lane>>4)*8+j, p=c
// wA [c][mt][lane][j] : m=mt*16+(lane&15), n=(lane>>4)*8+j, p=c
__global__ __launch_bounds__(256) void prep_kernel(
    const float* __restrict__ pooled, const float* __restrict__ b1w,
    const float* __restrict__ b1b, const float* __restrict__ b2w,
    const float* __restrict__ b2b, const float* __restrict__ weight,
    const float* __restrict__ a1w, float* __restrict__ bias,
    unsigned short* __restrict__ a1A, unsigned short* __restrict__ wA) {
    int tid = threadIdx.x;
    for (int idx = tid; idx < 9 * 512; idx += 256) {
        int j = idx & 7, l = (idx >> 3) & 63, c = idx >> 9;
        int o = l & 15, n = (l >> 4) * 8 + j;
        float v = (o < 9) ? a1w[(o * N_ + n) * 9 + c] : 0.f;
        a1A[idx] = f2bf(v);
    }
    for (int idx = tid; idx < 9 * 1024; idx += 256) {
        int j = idx & 7, l = (idx >> 3) & 63, mt = (idx >> 9) & 1, c = idx >> 10;
        int m = mt * 16 + (l & 15), n = (l >> 4) * 8 + j;
        wA[idx] = f2bf(weight[(m * N_ + n) * 9 + c]);
    }
    int b = tid >> 5, j = tid & 31;  // 8 x 32 = 256 threads exactly
    __shared__ float hsh[B_][N_];
    float s = b1b[j];
#pragma unroll
    for (int n = 0; n < N_; n++) s += pooled[b * N_ + n] * b1w[j * N_ + n];
    hsh[b][j] = fmaxf(s, 0.f);
    __syncthreads();
    float s2 = b2b[j];
#pragma unroll
    for (int q = 0; q < M_; q++) s2 += hsh[b][q] * b2w[j * M_ + q];
    bias[b * M_ + j] = s2;
}

// ---------- fused MFMA kernel: attention1 + attended conv + bias ----------
__global__ __launch_bounds__(256) void laconv_kernel(
    const float* __restrict__ x, const float* __restrict__ a1b,
    const float* __restrict__ a2w, const float* __restrict__ a2b,
    const float* __restrict__ a3w, const float* __restrict__ a3b,
    const unsigned short* __restrict__ a1A, const unsigned short* __restrict__ wA,
    const float* __restrict__ bias, float* __restrict__ out) {
    // xs[pos][n] bf16, pos = r*18+c (18x18 tile+halo), n-stride padded to 40
    __shared__ __align__(16) unsigned short xs[324 * 40];  // 25920 B
    __shared__ float att_buf[9 * 264];                     //  9504 B

    const int b = blockIdx.z;
    const int th0 = blockIdx.y * 16, tw0 = blockIdx.x * 16;
    const int tid = threadIdx.x;
    const int wv = tid >> 6, lane = tid & 63;
    const int tx = lane & 15, ks = lane >> 4;
    const float* xb = x + (size_t)b * N_ * HW * HW;

    // ---- stage x tile -> LDS, transposed to [pos][n], bf16 ----
    for (int it = tid; it < 324 * 4; it += 256) {
        int grp = it / 324;           // n-group: n = grp*8 + i
        int pos = it - grp * 324;
        int r = pos / 18, cc = pos - r * 18;
        int h = th0 + r - 1, wc = tw0 + cc - 1;
        bool in = ((unsigned)h < HW) && ((unsigned)wc < HW);
        const float* src = xb + (size_t)(grp * 8) * (HW * HW) + h * HW + wc;
        U8 t;
#pragma unroll
        for (int i = 0; i < 4; ++i) {
            float f0 = in ? src[(2 * i) * (HW * HW)] : 0.f;
            float f1 = in ? src[(2 * i + 1) * (HW * HW)] : 0.f;
            t.u[i] = (unsigned)f2bf(f0) | ((unsigned)f2bf(f1) << 16);
        }
        *(short8*)&xs[pos * 40 + grp * 8] = t.s;
    }
    __syncthreads();

    // per-lane base into xs: pixel (ty = wv*4+g, tx), k-slot ks
    const int pb = (wv * 4) * 720 + tx * 40 + ks * 8;
    const float4_ zero4 = {0.f, 0.f, 0.f, 0.f};

    // ---- attention1 conv via MFMA: aacc[o=ks*4+reg][pix=tx] per group ----
    float4_ aacc[4];
#pragma unroll
    for (int g = 0; g < 4; ++g) aacc[g] = zero4;
#pragma unroll
    for (int c = 0; c < 9; ++c) {
        short8 aA = ((const short8*)a1A)[c * 64 + lane];
        const int coff = (c / 3) * 720 + (c % 3) * 40;
#pragma unroll
        for (int g = 0; g < 4; ++g) {
            short8 bP = *(const short8*)&xs[pb + g * 720 + coff];
            aacc[g] = __builtin_amdgcn_mfma_f32_16x16x32_bf16(aA, bP, aacc[g], 0, 0, 0);
        }
    }
    // write raw conv results to att_buf[o][pix]
#pragma unroll
    for (int g = 0; g < 4; ++g) {
#pragma unroll
        for (int reg = 0; reg < 4; ++reg) {
            int o = ks * 4 + reg;
            if (o < 9) att_buf[o * 264 + (wv * 4 + g) * 16 + tx] = aacc[g][reg];
        }
    }
    __syncthreads();

    // ---- per-pixel MLP 9->9->9 + sigmoid (thread tid = pixel tid) ----
    float t1[9], t2[9], attv[9];
#pragma unroll
    for (int o = 0; o < 9; ++o)
        t1[o] = fmaxf(att_buf[o * 264 + tid] + a1b[o], 0.f);
#pragma unroll
    for (int o2 = 0; o2 < 9; ++o2) {
        float s = a2b[o2];
#pragma unroll
        for (int o = 0; o < 9; ++o) s += a2w[o2 * 9 + o] * t1[o];
        t2[o2] = fmaxf(s, 0.f);
    }
#pragma unroll
    for (int o3 = 0; o3 < 9; ++o3) {
        float s = a3b[o3];
#pragma unroll
        for (int o2 = 0; o2 < 9; ++o2) s += a3w[o3 * 9 + o2] * t2[o2];
        attv[o3] = 1.f / (1.f + __expf(-s));
    }
    __syncthreads();
#pragma unroll
    for (int p = 0; p < 9; ++p) att_buf[p * 264 + tid] = attv[p];
    __syncthreads();

    // ---- main einsum: per chunk c, z = W_c · pat_c (zero-C MFMA), then
    //      acc += att[c,pix] * z  in fp32 (att applied full-precision)
    float4_ acc0[4], acc1[4];
#pragma unroll
    for (int g = 0; g < 4; ++g) { acc0[g] = zero4; acc1[g] = zero4; }
#pragma unroll
    for (int c = 0; c < 9; ++c) {
        short8 w0 = ((const short8*)wA)[c * 128 + lane];
        short8 w1 = ((const short8*)wA)[c * 128 + 64 + lane];
        const int coff = (c / 3) * 720 + (c % 3) * 40;
#pragma unroll
        for (int g = 0; g < 4; ++g) {
            short8 bP = *(const short8*)&xs[pb + g * 720 + coff];
            float av = att_buf[c * 264 + (wv * 4 + g) * 16 + tx];
            float4_ z0 = __builtin_amdgcn_mfma_f32_16x16x32_bf16(w0, bP, zero4, 0, 0, 0);
            float4_ z1 = __builtin_amdgcn_mfma_f32_16x16x32_bf16(w1, bP, zero4, 0, 0, 0);
#pragma unroll
            for (int reg = 0; reg < 4; ++reg) {
                acc0[g][reg] += av * z0[reg];
                acc1[g][reg] += av * z1[reg];
            }
        }
    }

    // ---- epilogue: D row = m = mt*16 + ks*4 + reg, col = tx ----
    const int wc = tw0 + tx;
    float4_ bv0 = *(const float4_*)&bias[b * M_ + ks * 4];
    float4_ bv1 = *(const float4_*)&bias[b * M_ + 16 + ks * 4];
#pragma unroll
    for (int g = 0; g < 4; ++g) {
        int h = th0 + wv * 4 + g;
#pragma unroll
        for (int reg = 0; reg < 4; ++reg) {
            int m0 = ks * 4 + reg;
            out[((b * M_ + m0) * HW + h) * HW + wc] = acc0[g][reg] + bv0[reg];
            out[((b * M_ + m0 + 16) * HW + h) * HW + wc] = acc1[g][reg] + bv1[reg];
        }
    }
}

extern "C" void kernel_launch(void* const* d_in, const int* in_sizes, int n_in,
                              void* d_out, int out_size, void* d_ws,
                              size_t ws_size, hipStream_t stream) {
    const float* x   = (const float*)d_in[0];
    const float* a1w = (const float*)d_in[1];
    const float* a1b = (const float*)d_in[2];
    const float* a2w = (const float*)d_in[3];
    const float* a2b = (const float*)d_in[4];
    const float* a3w = (const float*)d_in[5];
    const float* a3b = (const float*)d_in[6];
    const float* b1w = (const float*)d_in[7];
    const float* b1b = (const float*)d_in[8];
    const float* b2w = (const float*)d_in[9];
    const float* b2b = (const float*)d_in[10];
    const float* wgt = (const float*)d_in[11];
    float* out = (float*)d_out;

    char* ws = (char*)d_ws;
    float* pooled        = (float*)(ws);                 // 1024 B
    float* biasv         = (float*)(ws + 1024);          // 1024 B
    unsigned short* a1A  = (unsigned short*)(ws + 2048); // 9216 B
    unsigned short* wAf  = (unsigned short*)(ws + 11264);// 18432 B

    pool_kernel<<<dim3(B_ * N_), dim3(256), 0, stream>>>(x, pooled);
    prep_kernel<<<dim3(1), dim3(256), 0, stream>>>(pooled, b1w, b1b, b2w, b2b,
                                                   wgt, a1w, biasv, a1A, wAf);
    laconv_kernel<<<dim3(12, 12, B_), dim3(256), 0, stream>>>(
        x, a1b, a2w, a2b, a3w, a3b, a1A, wAf, biasv, out);
    (void)in_sizes; (void)n_in; (void)out_size; (void)ws_size;
}

// Round 4
// 160.486 us; speedup vs baseline: 2.2787x; 1.0334x over previous
//
#include <hip/hip_runtime.h>
#include <math.h>

#define B_ 8
#define N_ 32
#define M_ 32
#define HW 192

typedef __attribute__((ext_vector_type(8))) short short8;
typedef __attribute__((ext_vector_type(4))) float float4_;

__device__ inline unsigned short f2bf(float f) {
    unsigned int b = __float_as_uint(f);
    b += 0x7FFF + ((b >> 16) & 1);   // RNE
    return (unsigned short)(b >> 16);
}

union U8 { short8 s; unsigned int u[4]; };

// ---- pool (blocks 0..255) + weight-fragment prep (block 256) ----
// a1A[c][lane][j] : o=lane&15 (o<9 real, else 0), n=(lane>>4)*8+j, p=c
// wA [c][mt][lane][j] : m=mt*16+(lane&15), n=(lane>>4)*8+j, p=c
__global__ __launch_bounds__(256) void pool_prep_kernel(
    const float* __restrict__ x, const float* __restrict__ a1w,
    const float* __restrict__ weight, float* __restrict__ pooled,
    unsigned short* __restrict__ a1A, unsigned short* __restrict__ wA) {
    if (blockIdx.x == 256) {  // prep block: build bf16 MFMA A-fragments
        int tid = threadIdx.x;
        for (int idx = tid; idx < 9 * 512; idx += 256) {
            int j = idx & 7, l = (idx >> 3) & 63, c = idx >> 9;
            int o = l & 15, n = (l >> 4) * 8 + j;
            float v = (o < 9) ? a1w[(o * N_ + n) * 9 + c] : 0.f;
            a1A[idx] = f2bf(v);
        }
        for (int idx = tid; idx < 9 * 1024; idx += 256) {
            int j = idx & 7, l = (idx >> 3) & 63, mt = (idx >> 9) & 1, c = idx >> 10;
            int m = mt * 16 + (l & 15), n = (l >> 4) * 8 + j;
            wA[idx] = f2bf(weight[(m * N_ + n) * 9 + c]);
        }
        return;
    }
    int bn = blockIdx.x;
    const float4_* p = (const float4_*)(x + (size_t)bn * (HW * HW));
    float s = 0.f;
    for (int i = threadIdx.x; i < (HW * HW) / 4; i += 256) {
        float4_ v = p[i];
        s += (v[0] + v[1]) + (v[2] + v[3]);
    }
#pragma unroll
    for (int off = 32; off > 0; off >>= 1) s += __shfl_down(s, off, 64);
    __shared__ float red[4];
    if ((threadIdx.x & 63) == 0) red[threadIdx.x >> 6] = s;
    __syncthreads();
    if (threadIdx.x == 0)
        pooled[bn] = (red[0] + red[1] + red[2] + red[3]) * (1.f / (HW * HW));
}

// ---------- fused MFMA kernel: attention1 + attended conv + bias ----------
__global__ __launch_bounds__(256) void laconv_kernel(
    const float* __restrict__ x, const float* __restrict__ a1b,
    const float* __restrict__ a2w, const float* __restrict__ a2b,
    const float* __restrict__ a3w, const float* __restrict__ a3b,
    const unsigned short* __restrict__ a1A, const unsigned short* __restrict__ wA,
    const float* __restrict__ pooled, const float* __restrict__ b1w,
    const float* __restrict__ b1b, const float* __restrict__ b2w,
    const float* __restrict__ b2b, float* __restrict__ out) {
    // xs[pos][n] bf16, pos = r*18+c (18x18 tile+halo), n-stride padded to 40
    __shared__ __align__(16) unsigned short xs[324 * 40];  // 25920 B
    __shared__ float att_buf[9 * 264];                     //  9504 B
    __shared__ float hsh[M_];
    __shared__ __align__(16) float bias_lds[M_];

    const int b = blockIdx.z;
    const int th0 = blockIdx.y * 16, tw0 = blockIdx.x * 16;
    const int tid = threadIdx.x;
    const int wv = tid >> 6, lane = tid & 63;
    const int tx = lane & 15, ks = lane >> 4;
    const float* xb = x + (size_t)b * N_ * HW * HW;

    // ---- stage x tile -> LDS, transposed to [pos][n], bf16 ----
    for (int it = tid; it < 324 * 4; it += 256) {
        int grp = it / 324;           // n-group: n = grp*8 + i
        int pos = it - grp * 324;
        int r = pos / 18, cc = pos - r * 18;
        int h = th0 + r - 1, wc = tw0 + cc - 1;
        bool in = ((unsigned)h < HW) && ((unsigned)wc < HW);
        const float* src = xb + (size_t)(grp * 8) * (HW * HW) + h * HW + wc;
        U8 t;
#pragma unroll
        for (int i = 0; i < 4; ++i) {
            float f0 = in ? src[(2 * i) * (HW * HW)] : 0.f;
            float f1 = in ? src[(2 * i + 1) * (HW * HW)] : 0.f;
            t.u[i] = (unsigned)f2bf(f0) | ((unsigned)f2bf(f1) << 16);
        }
        *(short8*)&xs[pos * 40 + grp * 8] = t.s;
    }
    // bias MLP stage 1 (overlaps staging; covered by the sync below)
    if (tid < M_) {
        float s = b1b[tid];
#pragma unroll
        for (int n = 0; n < N_; n++) s += pooled[b * N_ + n] * b1w[tid * N_ + n];
        hsh[tid] = fmaxf(s, 0.f);
    }
    __syncthreads();
    // bias MLP stage 2 (bias_lds read only after sync-3 below)
    if (tid < M_) {
        float s2 = b2b[tid];
#pragma unroll
        for (int q = 0; q < M_; q++) s2 += hsh[q] * b2w[tid * M_ + q];
        bias_lds[tid] = s2;
    }

    // per-lane base into xs: pixel (ty = wv*4+g, tx), k-slot ks
    const int pb = (wv * 4) * 720 + tx * 40 + ks * 8;
    const float4_ zero4 = {0.f, 0.f, 0.f, 0.f};

    // ---- attention1 conv via MFMA: aacc[o=ks*4+reg][pix=tx] per group ----
    float4_ aacc[4];
#pragma unroll
    for (int g = 0; g < 4; ++g) aacc[g] = zero4;
#pragma unroll
    for (int c = 0; c < 9; ++c) {
        short8 aA = ((const short8*)a1A)[c * 64 + lane];
        const int coff = (c / 3) * 720 + (c % 3) * 40;
#pragma unroll
        for (int g = 0; g < 4; ++g) {
            short8 bP = *(const short8*)&xs[pb + g * 720 + coff];
            aacc[g] = __builtin_amdgcn_mfma_f32_16x16x32_bf16(aA, bP, aacc[g], 0, 0, 0);
        }
    }
    // write raw conv results to att_buf[o][pix]
#pragma unroll
    for (int g = 0; g < 4; ++g) {
#pragma unroll
        for (int reg = 0; reg < 4; ++reg) {
            int o = ks * 4 + reg;
            if (o < 9) att_buf[o * 264 + (wv * 4 + g) * 16 + tx] = aacc[g][reg];
        }
    }
    __syncthreads();

    // ---- per-pixel MLP 9->9->9 + sigmoid (thread tid = pixel tid) ----
    float t1[9], t2[9], attv[9];
#pragma unroll
    for (int o = 0; o < 9; ++o)
        t1[o] = fmaxf(att_buf[o * 264 + tid] + a1b[o], 0.f);
#pragma unroll
    for (int o2 = 0; o2 < 9; ++o2) {
        float s = a2b[o2];
#pragma unroll
        for (int o = 0; o < 9; ++o) s += a2w[o2 * 9 + o] * t1[o];
        t2[o2] = fmaxf(s, 0.f);
    }
#pragma unroll
    for (int o3 = 0; o3 < 9; ++o3) {
        float s = a3b[o3];
#pragma unroll
        for (int o2 = 0; o2 < 9; ++o2) s += a3w[o3 * 9 + o2] * t2[o2];
        attv[o3] = 1.f / (1.f + __expf(-s));
    }
    __syncthreads();
#pragma unroll
    for (int p = 0; p < 9; ++p) att_buf[p * 264 + tid] = attv[p];
    __syncthreads();

    // ---- main einsum: per chunk c, z = W_c · pat_c (zero-C MFMA), then
    //      acc += att * z as float4 vector math (-> v_pk_fma_f32)
    float4_ acc0[4], acc1[4];
#pragma unroll
    for (int g = 0; g < 4; ++g) { acc0[g] = zero4; acc1[g] = zero4; }
#pragma unroll
    for (int c = 0; c < 9; ++c) {
        short8 w0 = ((const short8*)wA)[c * 128 + lane];
        short8 w1 = ((const short8*)wA)[c * 128 + 64 + lane];
        const int coff = (c / 3) * 720 + (c % 3) * 40;
#pragma unroll
        for (int g = 0; g < 4; ++g) {
            short8 bP = *(const short8*)&xs[pb + g * 720 + coff];
            float av = att_buf[c * 264 + (wv * 4 + g) * 16 + tx];
            float4_ av4 = {av, av, av, av};
            float4_ z0 = __builtin_amdgcn_mfma_f32_16x16x32_bf16(w0, bP, zero4, 0, 0, 0);
            float4_ z1 = __builtin_amdgcn_mfma_f32_16x16x32_bf16(w1, bP, zero4, 0, 0, 0);
            acc0[g] = acc0[g] + av4 * z0;
            acc1[g] = acc1[g] + av4 * z1;
        }
    }

    // ---- epilogue: D row = m = mt*16 + ks*4 + reg, col = tx ----
    const int wc = tw0 + tx;
    float4_ bv0 = *(const float4_*)&bias_lds[ks * 4];
    float4_ bv1 = *(const float4_*)&bias_lds[16 + ks * 4];
#pragma unroll
    for (int g = 0; g < 4; ++g) {
        int h = th0 + wv * 4 + g;
#pragma unroll
        for (int reg = 0; reg < 4; ++reg) {
            int m0 = ks * 4 + reg;
            out[((b * M_ + m0) * HW + h) * HW + wc] = acc0[g][reg] + bv0[reg];
            out[((b * M_ + m0 + 16) * HW + h) * HW + wc] = acc1[g][reg] + bv1[reg];
        }
    }
}

extern "C" void kernel_launch(void* const* d_in, const int* in_sizes, int n_in,
                              void* d_out, int out_size, void* d_ws,
                              size_t ws_size, hipStream_t stream) {
    const float* x   = (const float*)d_in[0];
    const float* a1w = (const float*)d_in[1];
    const float* a1b = (const float*)d_in[2];
    const float* a2w = (const float*)d_in[3];
    const float* a2b = (const float*)d_in[4];
    const float* a3w = (const float*)d_in[5];
    const float* a3b = (const float*)d_in[6];
    const float* b1w = (const float*)d_in[7];
    const float* b1b = (const float*)d_in[8];
    const float* b2w = (const float*)d_in[9];
    const float* b2b = (const float*)d_in[10];
    const float* wgt = (const float*)d_in[11];
    float* out = (float*)d_out;

    char* ws = (char*)d_ws;
    float* pooled        = (float*)(ws);                 // 1024 B
    unsigned short* a1A  = (unsigned short*)(ws + 2048); // 9216 B
    unsigned short* wAf  = (unsigned short*)(ws + 11264);// 18432 B

    pool_prep_kernel<<<dim3(B_ * N_ + 1), dim3(256), 0, stream>>>(
        x, a1w, wgt, pooled, a1A, wAf);
    laconv_kernel<<<dim3(12, 12, B_), dim3(256), 0, stream>>>(
        x, a1b, a2w, a2b, a3w, a3b, a1A, wAf, pooled, b1w, b1b, b2w, b2b, out);
    (void)in_sizes; (void)n_in; (void)out_size; (void)ws_size;
}

// Round 5
// 157.997 us; speedup vs baseline: 2.3146x; 1.0158x over previous
//
#include <hip/hip_runtime.h>
#include <math.h>

#define B_ 8
#define N_ 32
#define M_ 32
#define HW 192

typedef __attribute__((ext_vector_type(8))) short short8;
typedef __attribute__((ext_vector_type(4))) float float4_;

__device__ inline unsigned short f2bf(float f) {
    unsigned int b = __float_as_uint(f);
    b += 0x7FFF + ((b >> 16) & 1);   // RNE
    return (unsigned short)(b >> 16);
}
__device__ inline float bf2f(unsigned short u) {
    return __uint_as_float((unsigned int)u << 16);
}

union U8 { short8 s; unsigned int u[4]; };

// ---- pool (blocks 0..255) + weight-fragment prep (block 256) ----
// a1A[c][lane][j] : o=lane&15 (o<9 real, else 0), n=(lane>>4)*8+j, p=c
// wA [c][mt][lane][j] : m=mt*16+(lane&15), n=(lane>>4)*8+j, p=c
__global__ __launch_bounds__(256) void pool_prep_kernel(
    const float* __restrict__ x, const float* __restrict__ a1w,
    const float* __restrict__ weight, float* __restrict__ pooled,
    unsigned short* __restrict__ a1A, unsigned short* __restrict__ wA) {
    if (blockIdx.x == 256) {  // prep block: build bf16 MFMA A-fragments
        int tid = threadIdx.x;
        for (int idx = tid; idx < 9 * 512; idx += 256) {
            int j = idx & 7, l = (idx >> 3) & 63, c = idx >> 9;
            int o = l & 15, n = (l >> 4) * 8 + j;
            float v = (o < 9) ? a1w[(o * N_ + n) * 9 + c] : 0.f;
            a1A[idx] = f2bf(v);
        }
        for (int idx = tid; idx < 9 * 1024; idx += 256) {
            int j = idx & 7, l = (idx >> 3) & 63, mt = (idx >> 9) & 1, c = idx >> 10;
            int m = mt * 16 + (l & 15), n = (l >> 4) * 8 + j;
            wA[idx] = f2bf(weight[(m * N_ + n) * 9 + c]);
        }
        return;
    }
    int bn = blockIdx.x;
    const float4_* p = (const float4_*)(x + (size_t)bn * (HW * HW));
    float s = 0.f;
    for (int i = threadIdx.x; i < (HW * HW) / 4; i += 256) {
        float4_ v = p[i];
        s += (v[0] + v[1]) + (v[2] + v[3]);
    }
#pragma unroll
    for (int off = 32; off > 0; off >>= 1) s += __shfl_down(s, off, 64);
    __shared__ float red[4];
    if ((threadIdx.x & 63) == 0) red[threadIdx.x >> 6] = s;
    __syncthreads();
    if (threadIdx.x == 0)
        pooled[bn] = (red[0] + red[1] + red[2] + red[3]) * (1.f / (HW * HW));
}

// ---------- fused MFMA kernel: attention1 + attended conv + bias ----------
__global__ __launch_bounds__(256, 5) void laconv_kernel(
    const float* __restrict__ x, const float* __restrict__ a1b,
    const float* __restrict__ a2w, const float* __restrict__ a2b,
    const float* __restrict__ a3w, const float* __restrict__ a3b,
    const unsigned short* __restrict__ a1A, const unsigned short* __restrict__ wA,
    const float* __restrict__ pooled, const float* __restrict__ b1w,
    const float* __restrict__ b1b, const float* __restrict__ b2w,
    const float* __restrict__ b2b, float* __restrict__ out) {
    // xs[pos][n] bf16, pos = r*18+c (18x18 tile+halo), n-stride padded to 40
    __shared__ __align__(16) unsigned short xs[324 * 40];   // 25920 B
    __shared__ unsigned short att_s[9 * 264];               //  4752 B (bf16)
    __shared__ float hsh[M_];
    __shared__ __align__(16) float bias_lds[M_];            // total 30928 B -> 5 blk/CU

    const int b = blockIdx.z;
    const int th0 = blockIdx.y * 16, tw0 = blockIdx.x * 16;
    const int tid = threadIdx.x;
    const int wv = tid >> 6, lane = tid & 63;
    const int tx = lane & 15, ks = lane >> 4;
    const float* xb = x + (size_t)b * N_ * HW * HW;

    // ---- stage x tile -> LDS, transposed to [pos][n], bf16 ----
    // 6 static predicated iterations so all global loads pipeline
#pragma unroll
    for (int it0 = 0; it0 < 6; ++it0) {
        int it = tid + it0 * 256;
        if (it < 324 * 4) {
            int grp = it / 324;           // n-group: n = grp*8 + i
            int pos = it - grp * 324;
            int r = pos / 18, cc = pos - r * 18;
            int h = th0 + r - 1, wc = tw0 + cc - 1;
            bool in = ((unsigned)h < HW) && ((unsigned)wc < HW);
            const float* src = xb + (size_t)(grp * 8) * (HW * HW) + h * HW + wc;
            U8 t;
#pragma unroll
            for (int i = 0; i < 4; ++i) {
                float f0 = in ? src[(2 * i) * (HW * HW)] : 0.f;
                float f1 = in ? src[(2 * i + 1) * (HW * HW)] : 0.f;
                t.u[i] = (unsigned)f2bf(f0) | ((unsigned)f2bf(f1) << 16);
            }
            *(short8*)&xs[pos * 40 + grp * 8] = t.s;
        }
    }
    // bias MLP stage 1 (overlaps staging; covered by the sync below)
    if (tid < M_) {
        float s = b1b[tid];
#pragma unroll
        for (int n = 0; n < N_; n++) s += pooled[b * N_ + n] * b1w[tid * N_ + n];
        hsh[tid] = fmaxf(s, 0.f);
    }
    __syncthreads();
    // bias MLP stage 2 (bias_lds read only after later syncs)
    if (tid < M_) {
        float s2 = b2b[tid];
#pragma unroll
        for (int q = 0; q < M_; q++) s2 += hsh[q] * b2w[tid * M_ + q];
        bias_lds[tid] = s2;
    }

    // per-lane base into xs: pixel (ty = wv*4+g, tx), k-slot ks
    const int pb = (wv * 4) * 720 + tx * 40 + ks * 8;
    const float4_ zero4 = {0.f, 0.f, 0.f, 0.f};

    // ---- attention1 conv via MFMA: aacc[o=ks*4+reg][pix=tx] per group ----
    float4_ aacc[4];
#pragma unroll
    for (int g = 0; g < 4; ++g) aacc[g] = zero4;
#pragma unroll
    for (int c = 0; c < 9; ++c) {
        short8 aA = ((const short8*)a1A)[c * 64 + lane];
        const int coff = (c / 3) * 720 + (c % 3) * 40;
#pragma unroll
        for (int g = 0; g < 4; ++g) {
            short8 bP = *(const short8*)&xs[pb + g * 720 + coff];
            aacc[g] = __builtin_amdgcn_mfma_f32_16x16x32_bf16(aA, bP, aacc[g], 0, 0, 0);
        }
    }
    // write raw conv results (bf16) to att_s[o][pix]
#pragma unroll
    for (int g = 0; g < 4; ++g) {
#pragma unroll
        for (int reg = 0; reg < 4; ++reg) {
            int o = ks * 4 + reg;
            if (o < 9) att_s[o * 264 + (wv * 4 + g) * 16 + tx] = f2bf(aacc[g][reg]);
        }
    }
    __syncthreads();

    // ---- per-pixel MLP 9->9->9 + sigmoid (thread tid = pixel tid) ----
    float t1[9], t2[9], attv[9];
#pragma unroll
    for (int o = 0; o < 9; ++o)
        t1[o] = fmaxf(bf2f(att_s[o * 264 + tid]) + a1b[o], 0.f);
#pragma unroll
    for (int o2 = 0; o2 < 9; ++o2) {
        float s = a2b[o2];
#pragma unroll
        for (int o = 0; o < 9; ++o) s += a2w[o2 * 9 + o] * t1[o];
        t2[o2] = fmaxf(s, 0.f);
    }
#pragma unroll
    for (int o3 = 0; o3 < 9; ++o3) {
        float s = a3b[o3];
#pragma unroll
        for (int o2 = 0; o2 < 9; ++o2) s += a3w[o3 * 9 + o2] * t2[o2];
        attv[o3] = 1.f / (1.f + __expf(-s));
    }
    __syncthreads();
#pragma unroll
    for (int p = 0; p < 9; ++p) att_s[p * 264 + tid] = f2bf(attv[p]);
    __syncthreads();

    // ---- main einsum: per chunk c, z = W_c · pat_c (zero-C MFMA), then
    //      acc += att * z as float4 vector math (-> v_pk_fma_f32)
    float4_ acc0[4], acc1[4];
#pragma unroll
    for (int g = 0; g < 4; ++g) { acc0[g] = zero4; acc1[g] = zero4; }
#pragma unroll
    for (int c = 0; c < 9; ++c) {
        short8 w0 = ((const short8*)wA)[c * 128 + lane];
        short8 w1 = ((const short8*)wA)[c * 128 + 64 + lane];
        const int coff = (c / 3) * 720 + (c % 3) * 40;
#pragma unroll
        for (int g = 0; g < 4; ++g) {
            short8 bP = *(const short8*)&xs[pb + g * 720 + coff];
            float av = bf2f(att_s[c * 264 + (wv * 4 + g) * 16 + tx]);
            float4_ av4 = {av, av, av, av};
            float4_ z0 = __builtin_amdgcn_mfma_f32_16x16x32_bf16(w0, bP, zero4, 0, 0, 0);
            float4_ z1 = __builtin_amdgcn_mfma_f32_16x16x32_bf16(w1, bP, zero4, 0, 0, 0);
            acc0[g] = acc0[g] + av4 * z0;
            acc1[g] = acc1[g] + av4 * z1;
        }
    }

    // ---- epilogue: D row = m = mt*16 + ks*4 + reg, col = tx ----
    const int wc = tw0 + tx;
    float4_ bv0 = *(const float4_*)&bias_lds[ks * 4];
    float4_ bv1 = *(const float4_*)&bias_lds[16 + ks * 4];
#pragma unroll
    for (int g = 0; g < 4; ++g) {
        int h = th0 + wv * 4 + g;
#pragma unroll
        for (int reg = 0; reg < 4; ++reg) {
            int m0 = ks * 4 + reg;
            out[((b * M_ + m0) * HW + h) * HW + wc] = acc0[g][reg] + bv0[reg];
            out[((b * M_ + m0 + 16) * HW + h) * HW + wc] = acc1[g][reg] + bv1[reg];
        }
    }
}

extern "C" void kernel_launch(void* const* d_in, const int* in_sizes, int n_in,
                              void* d_out, int out_size, void* d_ws,
                              size_t ws_size, hipStream_t stream) {
    const float* x   = (const float*)d_in[0];
    const float* a1w = (const float*)d_in[1];
    const float* a1b = (const float*)d_in[2];
    const float* a2w = (const float*)d_in[3];
    const float* a2b = (const float*)d_in[4];
    const float* a3w = (const float*)d_in[5];
    const float* a3b = (const float*)d_in[6];
    const float* b1w = (const float*)d_in[7];
    const float* b1b = (const float*)d_in[8];
    const float* b2w = (const float*)d_in[9];
    const float* b2b = (const float*)d_in[10];
    const float* wgt = (const float*)d_in[11];
    float* out = (float*)d_out;

    char* ws = (char*)d_ws;
    float* pooled        = (float*)(ws);                 // 1024 B
    unsigned short* a1A  = (unsigned short*)(ws + 2048); // 9216 B
    unsigned short* wAf  = (unsigned short*)(ws + 11264);// 18432 B

    pool_prep_kernel<<<dim3(B_ * N_ + 1), dim3(256), 0, stream>>>(
        x, a1w, wgt, pooled, a1A, wAf);
    laconv_kernel<<<dim3(12, 12, B_), dim3(256), 0, stream>>>(
        x, a1b, a2w, a2b, a3w, a3b, a1A, wAf, pooled, b1w, b1b, b2w, b2b, out);
    (void)in_sizes; (void)n_in; (void)out_size; (void)ws_size;
}

// Round 6
// 139.307 us; speedup vs baseline: 2.6251x; 1.1342x over previous
//
#include <hip/hip_runtime.h>
#include <math.h>

#define B_ 8
#define N_ 32
#define M_ 32
#define HW 192

typedef __attribute__((ext_vector_type(8))) short short8;
typedef __attribute__((ext_vector_type(4))) float float4_;

__device__ inline unsigned short f2bf(float f) {
    unsigned int b = __float_as_uint(f);
    b += 0x7FFF + ((b >> 16) & 1);   // RNE
    return (unsigned short)(b >> 16);
}
__device__ inline float bf2f(unsigned short u) {
    return __uint_as_float((unsigned int)u << 16);
}

union U8 { short8 s; unsigned int u[4]; };

// ---- pool (blocks 0..255) + weight-fragment prep (block 256) ----
// a1A[c][lane][j] : o=lane&15 (o<9 real, else 0), n=(lane>>4)*8+j, p=c
// wA [c][mt][lane][j] : m=mt*16+(lane&15), n=(lane>>4)*8+j, p=c
__global__ __launch_bounds__(256) void pool_prep_kernel(
    const float* __restrict__ x, const float* __restrict__ a1w,
    const float* __restrict__ weight, float* __restrict__ pooled,
    unsigned short* __restrict__ a1A, unsigned short* __restrict__ wA) {
    if (blockIdx.x == 256) {  // prep block: build bf16 MFMA A-fragments
        int tid = threadIdx.x;
        for (int idx = tid; idx < 9 * 512; idx += 256) {
            int j = idx & 7, l = (idx >> 3) & 63, c = idx >> 9;
            int o = l & 15, n = (l >> 4) * 8 + j;
            float v = (o < 9) ? a1w[(o * N_ + n) * 9 + c] : 0.f;
            a1A[idx] = f2bf(v);
        }
        for (int idx = tid; idx < 9 * 1024; idx += 256) {
            int j = idx & 7, l = (idx >> 3) & 63, mt = (idx >> 9) & 1, c = idx >> 10;
            int m = mt * 16 + (l & 15), n = (l >> 4) * 8 + j;
            wA[idx] = f2bf(weight[(m * N_ + n) * 9 + c]);
        }
        return;
    }
    int bn = blockIdx.x;
    const float4_* p = (const float4_*)(x + (size_t)bn * (HW * HW));
    float s = 0.f;
    for (int i = threadIdx.x; i < (HW * HW) / 4; i += 256) {
        float4_ v = p[i];
        s += (v[0] + v[1]) + (v[2] + v[3]);
    }
#pragma unroll
    for (int off = 32; off > 0; off >>= 1) s += __shfl_down(s, off, 64);
    __shared__ float red[4];
    if ((threadIdx.x & 63) == 0) red[threadIdx.x >> 6] = s;
    __syncthreads();
    if (threadIdx.x == 0)
        pooled[bn] = (red[0] + red[1] + red[2] + red[3]) * (1.f / (HW * HW));
}

// ---------- fused MFMA kernel: attention1 + attended conv + bias ----------
__global__ __launch_bounds__(256) void laconv_kernel(
    const float* __restrict__ x, const float* __restrict__ a1b,
    const float* __restrict__ a2w, const float* __restrict__ a2b,
    const float* __restrict__ a3w, const float* __restrict__ a3b,
    const unsigned short* __restrict__ a1A, const unsigned short* __restrict__ wA,
    const float* __restrict__ pooled, const float* __restrict__ b1w,
    const float* __restrict__ b1b, const float* __restrict__ b2w,
    const float* __restrict__ b2b, float* __restrict__ out) {
    // xs[pos][n] bf16, pos = r*18+c (18x18 tile+halo), n-stride padded to 40
    __shared__ __align__(16) unsigned short xs[324 * 40];   // 25920 B
    __shared__ unsigned short att_s[9 * 264];               //  4752 B (bf16)
    __shared__ float hsh[M_];
    __shared__ __align__(16) float bias_lds[M_];            // ~30.9 KB -> 5 blk/CU

    // XCD-affinity swizzle: batch = id&7 (round-robin -> one image per XCD),
    // consecutive tiles of an image stay on the same XCD for halo L2 sharing.
    const int id = blockIdx.x;
    const int b = id & 7;
    const int t = id >> 3;           // 0..143
    const int bx = t % 12, by = t / 12;
    const int th0 = by * 16, tw0 = bx * 16;
    const int tid = threadIdx.x;
    const int wv = tid >> 6, lane = tid & 63;
    const int tx = lane & 15, ks = lane >> 4;
    const float* xb = x + (size_t)b * N_ * HW * HW;

    // ---- stage x tile -> LDS transposed [pos][n] bf16; loads-first ----
    float fv[5][8];
    int posv[5], grpv[5];
#pragma unroll
    for (int it0 = 0; it0 < 5; ++it0) {
        int it = tid + it0 * 256;          // < 1280
        int grp = it / 324;                // n-group: n = grp*8 + i
        int pos = it - grp * 324;
        posv[it0] = pos; grpv[it0] = grp;
        int r = pos / 18, cc = pos - r * 18;
        int h = th0 + r - 1, wc = tw0 + cc - 1;
        const float* src = xb + (size_t)(grp * 8) * (HW * HW) + h * HW + wc;
        if (((unsigned)h < HW) && ((unsigned)wc < HW)) {
#pragma unroll
            for (int i = 0; i < 8; ++i) fv[it0][i] = src[i * (HW * HW)];
        } else {
#pragma unroll
            for (int i = 0; i < 8; ++i) fv[it0][i] = 0.f;
        }
    }
    // remainder: it = 1280 + tid, tid < 16  (pos 956.. -> grp 3)
    float fr[8];
    int posr = 0;
    if (tid < 16) {
        int it = 1280 + tid;
        int pos = it - 3 * 324;
        posr = pos;
        int r = pos / 18, cc = pos - r * 18;
        int h = th0 + r - 1, wc = tw0 + cc - 1;
        const float* src = xb + (size_t)24 * (HW * HW) + h * HW + wc;
        if (((unsigned)h < HW) && ((unsigned)wc < HW)) {
#pragma unroll
            for (int i = 0; i < 8; ++i) fr[i] = src[i * (HW * HW)];
        } else {
#pragma unroll
            for (int i = 0; i < 8; ++i) fr[i] = 0.f;
        }
    }
    // pack + LDS write after all loads are in flight
#pragma unroll
    for (int it0 = 0; it0 < 5; ++it0) {
        U8 tt;
#pragma unroll
        for (int i = 0; i < 4; ++i)
            tt.u[i] = (unsigned)f2bf(fv[it0][2 * i]) |
                      ((unsigned)f2bf(fv[it0][2 * i + 1]) << 16);
        *(short8*)&xs[posv[it0] * 40 + grpv[it0] * 8] = tt.s;
    }
    if (tid < 16) {
        U8 tt;
#pragma unroll
        for (int i = 0; i < 4; ++i)
            tt.u[i] = (unsigned)f2bf(fr[2 * i]) | ((unsigned)f2bf(fr[2 * i + 1]) << 16);
        *(short8*)&xs[posr * 40 + 24] = tt.s;
    }
    // bias MLP stage 1 (covered by the sync below)
    if (tid < M_) {
        float s = b1b[tid];
#pragma unroll
        for (int n = 0; n < N_; n++) s += pooled[b * N_ + n] * b1w[tid * N_ + n];
        hsh[tid] = fmaxf(s, 0.f);
    }
    __syncthreads();
    // bias MLP stage 2 (bias_lds read only after the att sync below)
    if (tid < M_) {
        float s2 = b2b[tid];
#pragma unroll
        for (int q = 0; q < M_; q++) s2 += hsh[q] * b2w[tid * M_ + q];
        bias_lds[tid] = s2;
    }

    // per-lane base into xs: pixel (ty = wv*4+g, tx), k-slot ks
    const int pb = (wv * 4) * 720 + tx * 40 + ks * 8;
    const float4_ zero4 = {0.f, 0.f, 0.f, 0.f};

    // ---- attention1 conv via MFMA: aacc[o=ks*4+reg][pix=tx] per group ----
    float4_ aacc[4];
#pragma unroll
    for (int g = 0; g < 4; ++g) aacc[g] = zero4;
#pragma unroll
    for (int c = 0; c < 9; ++c) {
        short8 aA = ((const short8*)a1A)[c * 64 + lane];
        const int coff = (c / 3) * 720 + (c % 3) * 40;
#pragma unroll
        for (int g = 0; g < 4; ++g) {
            short8 bP = *(const short8*)&xs[pb + g * 720 + coff];
            aacc[g] = __builtin_amdgcn_mfma_f32_16x16x32_bf16(aA, bP, aacc[g], 0, 0, 0);
        }
    }
    // write raw conv results (bf16) to att_s[o][pix]
#pragma unroll
    for (int g = 0; g < 4; ++g) {
#pragma unroll
        for (int reg = 0; reg < 4; ++reg) {
            int o = ks * 4 + reg;
            if (o < 9) att_s[o * 264 + (wv * 4 + g) * 16 + tx] = f2bf(aacc[g][reg]);
        }
    }
    __syncthreads();

    // ---- per-pixel MLP 9->9->9 + sigmoid (thread tid = pixel tid) ----
    // reads & writes touch only column `tid` of att_s -> no barrier needed
    // between the read phase and the attv write-back.
    float t1[9], t2[9], attv[9];
#pragma unroll
    for (int o = 0; o < 9; ++o)
        t1[o] = fmaxf(bf2f(att_s[o * 264 + tid]) + a1b[o], 0.f);
#pragma unroll
    for (int o2 = 0; o2 < 9; ++o2) {
        float s = a2b[o2];
#pragma unroll
        for (int o = 0; o < 9; ++o) s += a2w[o2 * 9 + o] * t1[o];
        t2[o2] = fmaxf(s, 0.f);
    }
#pragma unroll
    for (int o3 = 0; o3 < 9; ++o3) {
        float s = a3b[o3];
#pragma unroll
        for (int o2 = 0; o2 < 9; ++o2) s += a3w[o3 * 9 + o2] * t2[o2];
        attv[o3] = 1.f / (1.f + __expf(-s));
    }
#pragma unroll
    for (int p = 0; p < 9; ++p) att_s[p * 264 + tid] = f2bf(attv[p]);
    __syncthreads();

    // ---- main einsum: per chunk c, z = W_c · pat_c (zero-C MFMA), then
    //      acc += att * z as float4 vector math (-> v_pk_fma_f32)
    float4_ acc0[4], acc1[4];
#pragma unroll
    for (int g = 0; g < 4; ++g) { acc0[g] = zero4; acc1[g] = zero4; }
#pragma unroll
    for (int c = 0; c < 9; ++c) {
        short8 w0 = ((const short8*)wA)[c * 128 + lane];
        short8 w1 = ((const short8*)wA)[c * 128 + 64 + lane];
        const int coff = (c / 3) * 720 + (c % 3) * 40;
#pragma unroll
        for (int g = 0; g < 4; ++g) {
            short8 bP = *(const short8*)&xs[pb + g * 720 + coff];
            float av = bf2f(att_s[c * 264 + (wv * 4 + g) * 16 + tx]);
            float4_ av4 = {av, av, av, av};
            float4_ z0 = __builtin_amdgcn_mfma_f32_16x16x32_bf16(w0, bP, zero4, 0, 0, 0);
            float4_ z1 = __builtin_amdgcn_mfma_f32_16x16x32_bf16(w1, bP, zero4, 0, 0, 0);
            acc0[g] = acc0[g] + av4 * z0;
            acc1[g] = acc1[g] + av4 * z1;
        }
    }

    // ---- epilogue: D row = m = mt*16 + ks*4 + reg, col = tx ----
    const int wc = tw0 + tx;
    float4_ bv0 = *(const float4_*)&bias_lds[ks * 4];
    float4_ bv1 = *(const float4_*)&bias_lds[16 + ks * 4];
#pragma unroll
    for (int g = 0; g < 4; ++g) {
        int h = th0 + wv * 4 + g;
#pragma unroll
        for (int reg = 0; reg < 4; ++reg) {
            int m0 = ks * 4 + reg;
            out[((b * M_ + m0) * HW + h) * HW + wc] = acc0[g][reg] + bv0[reg];
            out[((b * M_ + m0 + 16) * HW + h) * HW + wc] = acc1[g][reg] + bv1[reg];
        }
    }
}

extern "C" void kernel_launch(void* const* d_in, const int* in_sizes, int n_in,
                              void* d_out, int out_size, void* d_ws,
                              size_t ws_size, hipStream_t stream) {
    const float* x   = (const float*)d_in[0];
    const float* a1w = (const float*)d_in[1];
    const float* a1b = (const float*)d_in[2];
    const float* a2w = (const float*)d_in[3];
    const float* a2b = (const float*)d_in[4];
    const float* a3w = (const float*)d_in[5];
    const float* a3b = (const float*)d_in[6];
    const float* b1w = (const float*)d_in[7];
    const float* b1b = (const float*)d_in[8];
    const float* b2w = (const float*)d_in[9];
    const float* b2b = (const float*)d_in[10];
    const float* wgt = (const float*)d_in[11];
    float* out = (float*)d_out;

    char* ws = (char*)d_ws;
    float* pooled        = (float*)(ws);                 // 1024 B
    unsigned short* a1A  = (unsigned short*)(ws + 2048); // 9216 B
    unsigned short* wAf  = (unsigned short*)(ws + 11264);// 18432 B

    pool_prep_kernel<<<dim3(B_ * N_ + 1), dim3(256), 0, stream>>>(
        x, a1w, wgt, pooled, a1A, wAf);
    laconv_kernel<<<dim3(12 * 12 * B_), dim3(256), 0, stream>>>(
        x, a1b, a2w, a2b, a3w, a3b, a1A, wAf, pooled, b1w, b1b, b2w, b2b, out);
    (void)in_sizes; (void)n_in; (void)out_size; (void)ws_size;
}